// Round 5
// baseline (3095.776 us; speedup 1.0000x reference)
//
#include <hip/hip_runtime.h>
#include <stdint.h>

#define T_TOTAL 32
#define BATCH   1024
#define INDIM   784
#define HDIM    4096
#define OUTDIM  10
#define BH      (BATCH * HDIM)      // 4,194,304
#define WORDS_PER_T (BH / 64)       // 65,536 u64 words per timestep
#define NKSTEP  49                  // 784 / 16

// ---------------- W2 transpose: W2[10][4096] -> W2T[4096][10] ----------------
__global__ void k_transpose_w2(const float* __restrict__ W2, float* __restrict__ W2T) {
    int i = blockIdx.x * 256 + threadIdx.x;
    if (i < HDIM * OUTDIM) {
        int h = i / OUTDIM, o = i % OUTDIM;
        W2T[i] = W2[o * HDIM + h];
    }
}

// ---------------- fp32 GEMM: Z[m][n] = sum_k A[m][k]*B[n][k], ascending-k fma ----------------
// BM=128, BN=256, BK=16, 256 threads (16x16), 8x16 micro-tile.
// LDS k-major with pad: As[16][132], Bs[16][260]. B-fragment cols {tc*4 + g*64}.
// Register prefetch: next K-step's global loads issue before the fma phase.
// NOTE: per-element accumulation is ONE fma per k, k ascending -> bitwise identical
// to BLAS-style sgemm (and to the round-1 kernel that passed with absmax 0.0).
__global__ __launch_bounds__(256) void k_gemm_f32(const float* __restrict__ A,
                                                  const float* __restrict__ B,
                                                  float* __restrict__ Z) {
    __shared__ float As[16 * 132];   // 8448 B
    __shared__ float Bs[16 * 260];   // 16640 B

    // XCD-bijective swizzle (gridDim.x % 8 == 0 always: grid = Tc*128)
    const int cpx = gridDim.x >> 3;
    const int swz = (blockIdx.x & 7) * cpx + (blockIdx.x >> 3);
    const int nbm = gridDim.x >> 4;          // m-blocks (Mc/128)
    const int bm  = swz % nbm;               // consecutive swz share bn -> B panel L2-resident
    const int bn  = swz / nbm;

    const int tid = threadIdx.x;
    const int tc  = tid & 15;                // n-dir
    const int tr  = tid >> 4;                // m-dir

    const float* Ag = A + (size_t)bm * 128 * INDIM;
    const float* Bg = B + (size_t)bn * 256 * INDIM;

    // staging chunk ids: A: c = tid + 256*i (i<2), row=c>>2, kq=(c&3)*4
    //                    B: c = tid + 256*i (i<4)
    const int ar0 = tid >> 2,         ak0 = (tid & 3) << 2;
    const int ar1 = (tid + 256) >> 2, ak1 = ((tid + 256) & 3) << 2;   // row+64, same kq
    float4 ra0, ra1, rb0, rb1, rb2, rb3;

    // prefetch k-step 0
    ra0 = *(const float4*)(Ag + (size_t)ar0 * INDIM + ak0);
    ra1 = *(const float4*)(Ag + (size_t)ar1 * INDIM + ak1);
    {
        const int c0 = tid, c1 = tid + 256, c2 = tid + 512, c3 = tid + 768;
        rb0 = *(const float4*)(Bg + (size_t)(c0 >> 2) * INDIM + ((c0 & 3) << 2));
        rb1 = *(const float4*)(Bg + (size_t)(c1 >> 2) * INDIM + ((c1 & 3) << 2));
        rb2 = *(const float4*)(Bg + (size_t)(c2 >> 2) * INDIM + ((c2 & 3) << 2));
        rb3 = *(const float4*)(Bg + (size_t)(c3 >> 2) * INDIM + ((c3 & 3) << 2));
    }

    float4 acc[8][4];
#pragma unroll
    for (int i = 0; i < 8; ++i)
#pragma unroll
        for (int g = 0; g < 4; ++g) acc[i][g] = (float4){0.f, 0.f, 0.f, 0.f};

    for (int s = 0; s < NKSTEP; ++s) {
        __syncthreads();    // previous compute done reading LDS
        // write staged regs -> LDS (k-major transpose), 2-way-max bank aliasing
        As[(ak0 + 0) * 132 + ar0] = ra0.x;
        As[(ak0 + 1) * 132 + ar0] = ra0.y;
        As[(ak0 + 2) * 132 + ar0] = ra0.z;
        As[(ak0 + 3) * 132 + ar0] = ra0.w;
        As[(ak1 + 0) * 132 + ar1] = ra1.x;
        As[(ak1 + 1) * 132 + ar1] = ra1.y;
        As[(ak1 + 2) * 132 + ar1] = ra1.z;
        As[(ak1 + 3) * 132 + ar1] = ra1.w;
        {
            const int c0 = tid, c1 = tid + 256, c2 = tid + 512, c3 = tid + 768;
            float4 v; int r, kq;
            v = rb0; r = c0 >> 2; kq = (c0 & 3) << 2;
            Bs[(kq + 0) * 260 + r] = v.x; Bs[(kq + 1) * 260 + r] = v.y;
            Bs[(kq + 2) * 260 + r] = v.z; Bs[(kq + 3) * 260 + r] = v.w;
            v = rb1; r = c1 >> 2; kq = (c1 & 3) << 2;
            Bs[(kq + 0) * 260 + r] = v.x; Bs[(kq + 1) * 260 + r] = v.y;
            Bs[(kq + 2) * 260 + r] = v.z; Bs[(kq + 3) * 260 + r] = v.w;
            v = rb2; r = c2 >> 2; kq = (c2 & 3) << 2;
            Bs[(kq + 0) * 260 + r] = v.x; Bs[(kq + 1) * 260 + r] = v.y;
            Bs[(kq + 2) * 260 + r] = v.z; Bs[(kq + 3) * 260 + r] = v.w;
            v = rb3; r = c3 >> 2; kq = (c3 & 3) << 2;
            Bs[(kq + 0) * 260 + r] = v.x; Bs[(kq + 1) * 260 + r] = v.y;
            Bs[(kq + 2) * 260 + r] = v.z; Bs[(kq + 3) * 260 + r] = v.w;
        }
        __syncthreads();    // staged tile visible

        // issue next k-step's global loads; they complete under the fma phase
        if (s + 1 < NKSTEP) {
            const int k0n = (s + 1) * 16;
            ra0 = *(const float4*)(Ag + (size_t)ar0 * INDIM + k0n + ak0);
            ra1 = *(const float4*)(Ag + (size_t)ar1 * INDIM + k0n + ak1);
            const int c0 = tid, c1 = tid + 256, c2 = tid + 512, c3 = tid + 768;
            rb0 = *(const float4*)(Bg + (size_t)(c0 >> 2) * INDIM + k0n + ((c0 & 3) << 2));
            rb1 = *(const float4*)(Bg + (size_t)(c1 >> 2) * INDIM + k0n + ((c1 & 3) << 2));
            rb2 = *(const float4*)(Bg + (size_t)(c2 >> 2) * INDIM + k0n + ((c2 & 3) << 2));
            rb3 = *(const float4*)(Bg + (size_t)(c3 >> 2) * INDIM + k0n + ((c3 & 3) << 2));
        }

        // fma phase: 16 kk x 128 fma/thread, k ascending
#pragma unroll
        for (int kk = 0; kk < 16; ++kk) {
            const float* ap = &As[kk * 132 + tr * 8];
            float4 a0 = *(const float4*)ap;
            float4 a1 = *(const float4*)(ap + 4);
            const float* bp = &Bs[kk * 260 + tc * 4];
            float4 bb0 = *(const float4*)bp;
            float4 bb1 = *(const float4*)(bp + 64);
            float4 bb2 = *(const float4*)(bp + 128);
            float4 bb3 = *(const float4*)(bp + 192);
            float a[8] = {a0.x, a0.y, a0.z, a0.w, a1.x, a1.y, a1.z, a1.w};
            float4 bb[4] = {bb0, bb1, bb2, bb3};
#pragma unroll
            for (int i = 0; i < 8; ++i)
#pragma unroll
                for (int g = 0; g < 4; ++g) {
                    acc[i][g].x = fmaf(a[i], bb[g].x, acc[i][g].x);
                    acc[i][g].y = fmaf(a[i], bb[g].y, acc[i][g].y);
                    acc[i][g].z = fmaf(a[i], bb[g].z, acc[i][g].z);
                    acc[i][g].w = fmaf(a[i], bb[g].w, acc[i][g].w);
                }
        }
    }

    const int m0 = bm * 128 + tr * 8;
    const int n0 = bn * 256 + tc * 4;
#pragma unroll
    for (int i = 0; i < 8; ++i)
#pragma unroll
        for (int g = 0; g < 4; ++g)
            *(float4*)(Z + (size_t)(m0 + i) * HDIM + n0 + g * 64) = acc[i][g];
}

// ---------------- Layer-1 IF recurrence (ballot -> bitmask) ----------------
__global__ __launch_bounds__(256) void k_layer1(const float* __restrict__ Z,
                                                float* __restrict__ v1s,
                                                uint64_t* __restrict__ S1,
                                                int Tc, int first) {
    const size_t i = (size_t)blockIdx.x * 256 + threadIdx.x;
    float v = first ? 0.0f : v1s[i];
    const int lane = threadIdx.x & 63;
    const size_t word = i >> 6;
    for (int t = 0; t < Tc; ++t) {
        float z = Z[(size_t)t * BH + i];
        v += z;
        bool s = (v >= 1.0f);
        unsigned long long m = __ballot(s);
        if (lane == 0) S1[(size_t)t * WORDS_PER_T + word] = m;
        if (s) v = 0.0f;
    }
    v1s[i] = v;
}

// ---------------- Layer-2 partial sums from spike bitmask ----------------
__global__ __launch_bounds__(256) void k_layer2_partial(const uint64_t* __restrict__ S1,
                                                        const float* __restrict__ W2T,
                                                        float* __restrict__ part,
                                                        int rowsTotal) {
    __shared__ float w[1024][10];   // 40 KB
    const int hs = blockIdx.y;
    for (int i = threadIdx.x; i < 1024 * 10; i += 256)
        w[i / 10][i % 10] = W2T[hs * 1024 * 10 + i];
    __syncthreads();

    const int row = blockIdx.x * 256 + threadIdx.x;
    const uint64_t* wp = S1 + (size_t)row * 64 + hs * 16;
    float acc[10] = {};
    for (int wi = 0; wi < 16; ++wi) {
        uint64_t m = wp[wi];
        while (m) {
            int bit = __builtin_ctzll(m);
            m &= m - 1;
            int hl = wi * 64 + bit;
#pragma unroll
            for (int o = 0; o < 10; ++o) acc[o] += w[hl][o];
        }
    }
    float* p = part + ((size_t)hs * rowsTotal + row) * 10;
#pragma unroll
    for (int o = 0; o < 10; ++o) p[o] = acc[o];
}

// ---------------- Layer-2 IF recurrence + spike record ----------------
__global__ __launch_bounds__(256) void k_layer2_rec(const float* __restrict__ part,
                                                    float* __restrict__ v2s,
                                                    float* __restrict__ recs,
                                                    float* __restrict__ out,
                                                    int Tc, int first, int last) {
    const int i = blockIdx.x * 256 + threadIdx.x;
    if (i >= BATCH * OUTDIM) return;
    float v   = first ? 0.0f : v2s[i];
    float rec = first ? 0.0f : recs[i];
    const int rowsTotal = Tc * BATCH;
    const int b = i / OUTDIM, o = i % OUTDIM;
    for (int t = 0; t < Tc; ++t) {
        const int r = t * BATCH + b;
        float sig = 0.0f;
#pragma unroll
        for (int hs = 0; hs < 4; ++hs)
            sig += part[((size_t)hs * rowsTotal + r) * 10 + o];
        v += sig;
        bool s = (v >= 1.0f);
        rec += s ? 1.0f : 0.0f;
        if (s) v = 0.0f;
    }
    v2s[i] = v;
    recs[i] = rec;
    if (last) out[i] = rec;
}

// ---------------- launch ----------------
extern "C" void kernel_launch(void* const* d_in, const int* in_sizes, int n_in,
                              void* d_out, int out_size, void* d_ws, size_t ws_size,
                              hipStream_t stream) {
    (void)in_sizes; (void)n_in; (void)out_size;
    const float* x  = (const float*)d_in[0];   // [32][1024][784]
    const float* W1 = (const float*)d_in[1];   // [4096][784]
    const float* W2 = (const float*)d_in[2];   // [10][4096]
    float* out = (float*)d_out;                // [1024][10]

    const size_t szW2T = (size_t)HDIM * OUTDIM * 4;          // 163,840
    const size_t szV1  = (size_t)BH * 4;                     // 16,777,216
    const size_t szV2  = (size_t)BATCH * OUTDIM * 4;         // 40,960
    const size_t base  = szW2T + szV1 + 2 * szV2;
    const size_t perT  = (size_t)BH * 4                      // Z per step
                       + (size_t)WORDS_PER_T * 8             // S1 per step
                       + (size_t)4 * BATCH * OUTDIM * 4;     // part per step
    int Tc = 1;
    const int cands[6] = {32, 16, 8, 4, 2, 1};
    for (int ci = 0; ci < 6; ++ci)
        if (base + (size_t)cands[ci] * perT <= ws_size) { Tc = cands[ci]; break; }
    const int Mc = Tc * BATCH;

    char* p = (char*)d_ws;
    float*    W2T  = (float*)p;     p += szW2T;
    float*    v1s  = (float*)p;     p += szV1;
    float*    v2s  = (float*)p;     p += szV2;
    float*    recs = (float*)p;     p += szV2;
    float*    Z    = (float*)p;     p += (size_t)Tc * BH * 4;
    uint64_t* S1   = (uint64_t*)p;  p += (size_t)Tc * WORDS_PER_T * 8;
    float*    part = (float*)p;

    k_transpose_w2<<<(HDIM * OUTDIM + 255) / 256, 256, 0, stream>>>(W2, W2T);

    const int nch = T_TOTAL / Tc;
    for (int c = 0; c < nch; ++c) {
        const float* Ac = x + (size_t)c * Mc * INDIM;
        k_gemm_f32<<<(Mc / 128) * (HDIM / 256), 256, 0, stream>>>(Ac, W1, Z);
        k_layer1<<<BH / 256, 256, 0, stream>>>(Z, v1s, S1, Tc, c == 0);
        k_layer2_partial<<<dim3(Tc * 4, 4), 256, 0, stream>>>(S1, W2T, part, Tc * BATCH);
        k_layer2_rec<<<(BATCH * OUTDIM + 255) / 256, 256, 0, stream>>>(
            part, v2s, recs, out, Tc, c == 0, c == nch - 1);
    }
}

// Round 6
// 2496.743 us; speedup vs baseline: 1.2399x; 1.2399x over previous
//
#include <hip/hip_runtime.h>
#include <stdint.h>

#define T_TOTAL 32
#define BATCH   1024
#define INDIM   784
#define HDIM    4096
#define OUTDIM  10
#define BH      (BATCH * HDIM)      // 4,194,304
#define WORDS_PER_T (BH / 64)       // 65,536 u64 words per timestep
#define NKSTEP  49                  // 784 / 16

// ---------------- W2 transpose: W2[10][4096] -> W2T[4096][10] ----------------
__global__ void k_transpose_w2(const float* __restrict__ W2, float* __restrict__ W2T) {
    int i = blockIdx.x * 256 + threadIdx.x;
    if (i < HDIM * OUTDIM) {
        int h = i / OUTDIM, o = i % OUTDIM;
        W2T[i] = W2[o * HDIM + h];
    }
}

// ---------------- fp32 GEMM: Z[m][n] = sum_k A[m][k]*B[n][k], ascending-k fma ----------------
// Round-1 geometry (BM=BN=128, BK=16, 256 thr, 8x8 micro-tile, ~64-reg acc) with two fixes:
//  (1) B-fragment cols {tc*4, tc*4+64}: 2-way LDS aliasing (free) vs round-1's 4-way conflict.
//      A-fragment reads are 16-way broadcasts (tr in 0..3 per wave) - free either way.
//  (2) register prefetch: next K-step's 4 global float4 loads issue before the fma phase.
// Accumulation: ONE fma per k, k ascending -> bitwise identical to round-1 / OpenBLAS sgemm.
__global__ __launch_bounds__(256) void k_gemm_f32(const float* __restrict__ A,
                                                  const float* __restrict__ B,
                                                  float* __restrict__ Z) {
    __shared__ float As[16 * 132];   // [k][m], 8448 B
    __shared__ float Bs[16 * 132];   // [k][n], 8448 B

    // XCD-bijective swizzle (gridDim.x = (Mc/128)*32, always % 8 == 0)
    const int cpx = gridDim.x >> 3;
    const int swz = (blockIdx.x & 7) * cpx + (blockIdx.x >> 3);
    const int nbm = gridDim.x >> 5;          // m-blocks (Mc/128)
    const int bm  = swz % nbm;               // consecutive swz share bn -> B panel stays hot
    const int bn  = swz / nbm;

    const int tid = threadIdx.x;
    const int tc  = tid & 15;                // n-dir
    const int tr  = tid >> 4;                // m-dir

    const float* Ag = A + (size_t)bm * 128 * INDIM;
    const float* Bg = B + (size_t)bn * 128 * INDIM;

    // staging: thread covers rows r0 and r0+64, k-quad kq (8 floats of A, 8 of B per step)
    const int r0 = tid >> 2;                 // 0..63
    const int r1 = r0 + 64;
    const int kq = (tid & 3) << 2;           // 0,4,8,12
    float4 ra0, ra1, rb0, rb1;

    // prefetch k-step 0
    ra0 = *(const float4*)(Ag + (size_t)r0 * INDIM + kq);
    ra1 = *(const float4*)(Ag + (size_t)r1 * INDIM + kq);
    rb0 = *(const float4*)(Bg + (size_t)r0 * INDIM + kq);
    rb1 = *(const float4*)(Bg + (size_t)r1 * INDIM + kq);

    float4 acc[8][2];
#pragma unroll
    for (int i = 0; i < 8; ++i)
#pragma unroll
        for (int g = 0; g < 2; ++g) acc[i][g] = (float4){0.f, 0.f, 0.f, 0.f};

    for (int s = 0; s < NKSTEP; ++s) {
        __syncthreads();    // previous compute done reading LDS
        // regs -> LDS k-major transpose (2-way-max bank aliasing: row strides 132)
        As[(kq + 0) * 132 + r0] = ra0.x;
        As[(kq + 1) * 132 + r0] = ra0.y;
        As[(kq + 2) * 132 + r0] = ra0.z;
        As[(kq + 3) * 132 + r0] = ra0.w;
        As[(kq + 0) * 132 + r1] = ra1.x;
        As[(kq + 1) * 132 + r1] = ra1.y;
        As[(kq + 2) * 132 + r1] = ra1.z;
        As[(kq + 3) * 132 + r1] = ra1.w;
        Bs[(kq + 0) * 132 + r0] = rb0.x;
        Bs[(kq + 1) * 132 + r0] = rb0.y;
        Bs[(kq + 2) * 132 + r0] = rb0.z;
        Bs[(kq + 3) * 132 + r0] = rb0.w;
        Bs[(kq + 0) * 132 + r1] = rb1.x;
        Bs[(kq + 1) * 132 + r1] = rb1.y;
        Bs[(kq + 2) * 132 + r1] = rb1.z;
        Bs[(kq + 3) * 132 + r1] = rb1.w;
        __syncthreads();    // staged tile visible

        // issue next k-step's global loads; they complete under the fma phase
        if (s + 1 < NKSTEP) {
            const int kn = (s + 1) * 16 + kq;
            ra0 = *(const float4*)(Ag + (size_t)r0 * INDIM + kn);
            ra1 = *(const float4*)(Ag + (size_t)r1 * INDIM + kn);
            rb0 = *(const float4*)(Bg + (size_t)r0 * INDIM + kn);
            rb1 = *(const float4*)(Bg + (size_t)r1 * INDIM + kn);
        }

        // fma phase: 16 kk x 64 fma/thread, k ascending
#pragma unroll
        for (int kk = 0; kk < 16; ++kk) {
            const float* ap = &As[kk * 132 + tr * 8];
            float4 a0 = *(const float4*)ap;          // broadcast (4 addrs/wave)
            float4 a1 = *(const float4*)(ap + 4);
            const float* bp = &Bs[kk * 132 + tc * 4];
            float4 b0 = *(const float4*)bp;          // 2-way aliasing: free
            float4 b1 = *(const float4*)(bp + 64);
            float a[8] = {a0.x, a0.y, a0.z, a0.w, a1.x, a1.y, a1.z, a1.w};
#pragma unroll
            for (int i = 0; i < 8; ++i) {
                acc[i][0].x = fmaf(a[i], b0.x, acc[i][0].x);
                acc[i][0].y = fmaf(a[i], b0.y, acc[i][0].y);
                acc[i][0].z = fmaf(a[i], b0.z, acc[i][0].z);
                acc[i][0].w = fmaf(a[i], b0.w, acc[i][0].w);
                acc[i][1].x = fmaf(a[i], b1.x, acc[i][1].x);
                acc[i][1].y = fmaf(a[i], b1.y, acc[i][1].y);
                acc[i][1].z = fmaf(a[i], b1.z, acc[i][1].z);
                acc[i][1].w = fmaf(a[i], b1.w, acc[i][1].w);
            }
        }
    }

    const int m0 = bm * 128 + tr * 8;
    const int n0 = bn * 128 + tc * 4;
#pragma unroll
    for (int i = 0; i < 8; ++i) {
        *(float4*)(Z + (size_t)(m0 + i) * HDIM + n0)      = acc[i][0];
        *(float4*)(Z + (size_t)(m0 + i) * HDIM + n0 + 64) = acc[i][1];
    }
}

// ---------------- Layer-1 IF recurrence (ballot -> bitmask) ----------------
__global__ __launch_bounds__(256) void k_layer1(const float* __restrict__ Z,
                                                float* __restrict__ v1s,
                                                uint64_t* __restrict__ S1,
                                                int Tc, int first) {
    const size_t i = (size_t)blockIdx.x * 256 + threadIdx.x;
    float v = first ? 0.0f : v1s[i];
    const int lane = threadIdx.x & 63;
    const size_t word = i >> 6;
    for (int t = 0; t < Tc; ++t) {
        float z = Z[(size_t)t * BH + i];
        v += z;
        bool s = (v >= 1.0f);
        unsigned long long m = __ballot(s);
        if (lane == 0) S1[(size_t)t * WORDS_PER_T + word] = m;
        if (s) v = 0.0f;
    }
    v1s[i] = v;
}

// ---------------- Layer-2 partial sums from spike bitmask ----------------
__global__ __launch_bounds__(256) void k_layer2_partial(const uint64_t* __restrict__ S1,
                                                        const float* __restrict__ W2T,
                                                        float* __restrict__ part,
                                                        int rowsTotal) {
    __shared__ float w[1024][10];   // 40 KB
    const int hs = blockIdx.y;
    for (int i = threadIdx.x; i < 1024 * 10; i += 256)
        w[i / 10][i % 10] = W2T[hs * 1024 * 10 + i];
    __syncthreads();

    const int row = blockIdx.x * 256 + threadIdx.x;
    const uint64_t* wp = S1 + (size_t)row * 64 + hs * 16;
    float acc[10] = {};
    for (int wi = 0; wi < 16; ++wi) {
        uint64_t m = wp[wi];
        while (m) {
            int bit = __builtin_ctzll(m);
            m &= m - 1;
            int hl = wi * 64 + bit;
#pragma unroll
            for (int o = 0; o < 10; ++o) acc[o] += w[hl][o];
        }
    }
    float* p = part + ((size_t)hs * rowsTotal + row) * 10;
#pragma unroll
    for (int o = 0; o < 10; ++o) p[o] = acc[o];
}

// ---------------- Layer-2 IF recurrence + spike record ----------------
__global__ __launch_bounds__(256) void k_layer2_rec(const float* __restrict__ part,
                                                    float* __restrict__ v2s,
                                                    float* __restrict__ recs,
                                                    float* __restrict__ out,
                                                    int Tc, int first, int last) {
    const int i = blockIdx.x * 256 + threadIdx.x;
    if (i >= BATCH * OUTDIM) return;
    float v   = first ? 0.0f : v2s[i];
    float rec = first ? 0.0f : recs[i];
    const int rowsTotal = Tc * BATCH;
    const int b = i / OUTDIM, o = i % OUTDIM;
    for (int t = 0; t < Tc; ++t) {
        const int r = t * BATCH + b;
        float sig = 0.0f;
#pragma unroll
        for (int hs = 0; hs < 4; ++hs)
            sig += part[((size_t)hs * rowsTotal + r) * 10 + o];
        v += sig;
        bool s = (v >= 1.0f);
        rec += s ? 1.0f : 0.0f;
        if (s) v = 0.0f;
    }
    v2s[i] = v;
    recs[i] = rec;
    if (last) out[i] = rec;
}

// ---------------- launch ----------------
extern "C" void kernel_launch(void* const* d_in, const int* in_sizes, int n_in,
                              void* d_out, int out_size, void* d_ws, size_t ws_size,
                              hipStream_t stream) {
    (void)in_sizes; (void)n_in; (void)out_size;
    const float* x  = (const float*)d_in[0];   // [32][1024][784]
    const float* W1 = (const float*)d_in[1];   // [4096][784]
    const float* W2 = (const float*)d_in[2];   // [10][4096]
    float* out = (float*)d_out;                // [1024][10]

    const size_t szW2T = (size_t)HDIM * OUTDIM * 4;          // 163,840
    const size_t szV1  = (size_t)BH * 4;                     // 16,777,216
    const size_t szV2  = (size_t)BATCH * OUTDIM * 4;         // 40,960
    const size_t base  = szW2T + szV1 + 2 * szV2;
    const size_t perT  = (size_t)BH * 4                      // Z per step
                       + (size_t)WORDS_PER_T * 8             // S1 per step
                       + (size_t)4 * BATCH * OUTDIM * 4;     // part per step
    int Tc = 1;
    const int cands[6] = {32, 16, 8, 4, 2, 1};
    for (int ci = 0; ci < 6; ++ci)
        if (base + (size_t)cands[ci] * perT <= ws_size) { Tc = cands[ci]; break; }
    const int Mc = Tc * BATCH;

    char* p = (char*)d_ws;
    float*    W2T  = (float*)p;     p += szW2T;
    float*    v1s  = (float*)p;     p += szV1;
    float*    v2s  = (float*)p;     p += szV2;
    float*    recs = (float*)p;     p += szV2;
    float*    Z    = (float*)p;     p += (size_t)Tc * BH * 4;
    uint64_t* S1   = (uint64_t*)p;  p += (size_t)Tc * WORDS_PER_T * 8;
    float*    part = (float*)p;

    k_transpose_w2<<<(HDIM * OUTDIM + 255) / 256, 256, 0, stream>>>(W2, W2T);

    const int nch = T_TOTAL / Tc;
    for (int c = 0; c < nch; ++c) {
        const float* Ac = x + (size_t)c * Mc * INDIM;
        k_gemm_f32<<<(Mc / 128) * (HDIM / 128), 256, 0, stream>>>(Ac, W1, Z);
        k_layer1<<<BH / 256, 256, 0, stream>>>(Z, v1s, S1, Tc, c == 0);
        k_layer2_partial<<<dim3(Tc * 4, 4), 256, 0, stream>>>(S1, W2T, part, Tc * BATCH);
        k_layer2_rec<<<(BATCH * OUTDIM + 255) / 256, 256, 0, stream>>>(
            part, v2s, recs, out, Tc, c == 0, c == nch - 1);
    }
}